// Round 3
// baseline (274.795 us; speedup 1.0000x reference)
//
#include <hip/hip_runtime.h>
#include <hip/hip_bf16.h>

// WindowAttention fused bf16-MFMA implementation.
// Inputs fp32 (per reference), compute in bf16 MFMA, OUTPUT fp32.
// B=1024 windows, N=64 tokens, H=8 heads, hd=32, DIM=256, P=4.
// Fourier biases (azimuth + radius) folded into QK^T as 16 extra K-dims:
//   A_r[i,j,h]  = sum_p c_pi*(a c_pj + b s_pj)/P + s_pi*(a s_pj - b c_pj)/P   (rad = Dj-Di)
//   A_phi[i,j,h]= sum_p cf_pi*(a cf_pj - b sf_pj)/P + sf_pi*(a sf_pj + b cf_pj)/P (az = coli-colj)
// Head-constant terms a_r[0,h], a_p[0,h] are softmax-invariant and dropped.

using short8  = __attribute__((ext_vector_type(8))) short;
using floatx4 = __attribute__((ext_vector_type(4))) float;

#define PI_F    3.14159265358979323846f
#define SCALE_F 0.17677669529663687f   // 32^-0.5

// ---------------- kernel 1: weights fp32 -> bf16 into ws ----------------
__global__ void prep_kernel(const float* __restrict__ qw,
                            const float* __restrict__ pw,
                            __hip_bfloat16* __restrict__ dst) {
  int g = blockIdx.x * 256 + threadIdx.x;  // 65536 threads, one float4 each
  const float4* src;
  __hip_bfloat16* d;
  if (g < 49152) { src = (const float4*)qw + g; d = dst + g * 4; }
  else { int g2 = g - 49152; src = (const float4*)pw + g2; d = dst + 196608 + g2 * 4; }
  float4 v = *src;
  d[0] = __float2bfloat16(v.x);
  d[1] = __float2bfloat16(v.y);
  d[2] = __float2bfloat16(v.z);
  d[3] = __float2bfloat16(v.w);
}

// ---------------- kernel 2: fused qkv + biased attention per window ----------------
__global__ __launch_bounds__(256, 2) void attn_kernel(
    const float* __restrict__ x, const float* __restrict__ D,
    const float* __restrict__ a_p, const float* __restrict__ b_p,
    const float* __restrict__ a_r, const float* __restrict__ b_r,
    const __hip_bfloat16* __restrict__ wq, const float* __restrict__ qkv_b,
    __hip_bfloat16* __restrict__ Obuf)
{
  constexpr int LDX = 264, LDQ = 72, LDV = 72, LDP = 72;  // strides: +4 banks/row (2-way = free)
  __shared__ __align__(16) __hip_bfloat16 sX[64 * LDX];   // x window, bf16
  __shared__ __align__(16) __hip_bfloat16 sQ[64 * LDQ];   // Q~ : [0:32) scale*q, [32:48) feats, [48:64) zero
  __shared__ __align__(16) __hip_bfloat16 sK[64 * LDQ];   // K~ : [0:32) k,       [32:48) mixed, [48:64) zero
  __shared__ __align__(16) __hip_bfloat16 sVt[32 * LDV];  // V^T : [dim][token]
  __shared__ __align__(16) __hip_bfloat16 sP[64 * LDP];   // softmax probs
  __shared__ float sF[64 * 16];                           // per-token raw features

  const int tid = threadIdx.x;
  const int lane = tid & 63, w = tid >> 6;
  const int laneN = lane & 15, laneQ = lane >> 4;
  const int b = blockIdx.x;

  // ---- stage x -> sX (fp32 -> bf16) ----
  const float4* xg = (const float4*)(x + (size_t)b * 64 * 256);
  #pragma unroll
  for (int it = 0; it < 16; ++it) {
    int g = tid + it * 256;
    float4 v = xg[g];
    int t = g >> 6, c = (g & 63) * 4;
    __hip_bfloat16* p = &sX[t * LDX + c];
    p[0] = __float2bfloat16(v.x); p[1] = __float2bfloat16(v.y);
    p[2] = __float2bfloat16(v.z); p[3] = __float2bfloat16(v.w);
  }

  // ---- per-token Fourier features + static parts of sQ/sK ----
  if (tid < 64) {
    int t = tid;
    float dv = D[b * 64 + t];
    float s1, c1; __sincosf(PI_F * dv, &s1, &c1);
    float c2 = c1*c1 - s1*s1, s2 = 2.f*s1*c1;
    float c3 = c2*c1 - s2*s1, s3 = s2*c1 + c2*s1;
    float c4 = c2*c2 - s2*s2, s4 = 2.f*s2*c2;
    float colf = (float)(t & 7);
    float sa1, ca1; __sincosf((2.f * PI_F / 64.f) * colf, &sa1, &ca1);
    float ca2 = ca1*ca1 - sa1*sa1, sa2 = 2.f*sa1*ca1;
    float ca3 = ca2*ca1 - sa2*sa1, sa3 = sa2*ca1 + ca2*sa1;
    float ca4 = ca2*ca2 - sa2*sa2, sa4 = 2.f*sa2*ca2;
    float* f = &sF[t * 16];
    f[0]=c1;  f[1]=c2;  f[2]=c3;  f[3]=c4;
    f[4]=s1;  f[5]=s2;  f[6]=s3;  f[7]=s4;
    f[8]=ca1; f[9]=ca2; f[10]=ca3; f[11]=ca4;
    f[12]=sa1; f[13]=sa2; f[14]=sa3; f[15]=sa4;
    #pragma unroll
    for (int i = 0; i < 16; ++i) sQ[t * LDQ + 32 + i] = __float2bfloat16(f[i]);
    #pragma unroll
    for (int i = 48; i < 64; ++i) {
      sQ[t * LDQ + i] = __float2bfloat16(0.f);
      sK[t * LDQ + i] = __float2bfloat16(0.f);
    }
  }
  __syncthreads();

  const int mtA = (w & 1) * 2;   // qkv GEMM: row-stripe pair base
  const int ntA = (w >> 1) * 3;  // qkv GEMM: col-tile triple base
  const int m0s = w * 16;        // attention: softmax stripe base
  const floatx4 fzero = {0.f, 0.f, 0.f, 0.f};

  for (int h = 0; h < 8; ++h) {
    // ---- K~ coefficient mixing for this head: thread -> (token, p) ----
    {
      int t = tid >> 2, p = tid & 3;
      float ar = a_r[(p + 1) * 8 + h], br = b_r[p * 8 + h];
      float ap = a_p[(p + 1) * 8 + h], bp = b_p[p * 8 + h];
      const float* f = &sF[t * 16];
      float cr = f[p], sr = f[4 + p], ca = f[8 + p], sa = f[12 + p];
      sK[t * LDQ + 32 + p] = __float2bfloat16((ar * cr + br * sr) * 0.25f);
      sK[t * LDQ + 36 + p] = __float2bfloat16((ar * sr - br * cr) * 0.25f);
      sK[t * LDQ + 40 + p] = __float2bfloat16((ap * ca - bp * sa) * 0.25f);
      sK[t * LDQ + 44 + p] = __float2bfloat16((ap * sa + bp * ca) * 0.25f);
    }

    // ---- per-head qkv GEMM: (64x256)@(256x96), wave = 2 row-stripes x 3 col-tiles ----
    short8 afa[8], afb[8];
    #pragma unroll
    for (int kk = 0; kk < 8; ++kk) {
      afa[kk] = *(const short8*)&sX[(mtA * 16 + laneN) * LDX + kk * 32 + laneQ * 8];
      afb[kk] = *(const short8*)&sX[((mtA + 1) * 16 + laneN) * LDX + kk * 32 + laneQ * 8];
    }
    #pragma unroll
    for (int ni = 0; ni < 3; ++ni) {
      int nt = ntA + ni;
      int col0 = (nt < 2) ? h * 32 + nt * 16
               : (nt < 4) ? 256 + h * 32 + (nt - 2) * 16
                          : 512 + h * 32 + (nt - 4) * 16;
      float bias = qkv_b[col0 + laneN];
      short8 bf[8];
      #pragma unroll
      for (int kk = 0; kk < 8; ++kk)
        bf[kk] = *(const short8*)&wq[(size_t)(col0 + laneN) * 256 + kk * 32 + laneQ * 8];
      floatx4 acc0 = fzero, acc1 = fzero;
      #pragma unroll
      for (int kk = 0; kk < 8; ++kk) {
        acc0 = __builtin_amdgcn_mfma_f32_16x16x32_bf16(afa[kk], bf[kk], acc0, 0, 0, 0);
        acc1 = __builtin_amdgcn_mfma_f32_16x16x32_bf16(afb[kk], bf[kk], acc1, 0, 0, 0);
      }
      #pragma unroll
      for (int mi = 0; mi < 2; ++mi) {
        floatx4 acc = mi ? acc1 : acc0;
        #pragma unroll
        for (int r = 0; r < 4; ++r) {
          int row = (mtA + mi) * 16 + laneQ * 4 + r;   // C-layout: col=laneN, row=laneQ*4+r
          float v = acc[r] + bias;
          if (nt < 2)
            sQ[row * LDQ + nt * 16 + laneN] = __float2bfloat16(v * SCALE_F);
          else if (nt < 4)
            sK[row * LDQ + (nt - 2) * 16 + laneN] = __float2bfloat16(v);
          else
            sVt[((nt - 4) * 16 + laneN) * LDV + row] = __float2bfloat16(v);
        }
      }
    }
    __syncthreads();   // qkv + K~ mixing visible to all waves

    // ---- S = Q~ @ K~^T  (K=64: dims 0..31 qk, 32..47 bias feats, 48..63 zero) ----
    short8 qf[2];
    #pragma unroll
    for (int kk = 0; kk < 2; ++kk)
      qf[kk] = *(const short8*)&sQ[(m0s + laneN) * LDQ + kk * 32 + laneQ * 8];
    floatx4 s[4];
    #pragma unroll
    for (int nt = 0; nt < 4; ++nt) {
      s[nt] = fzero;
      #pragma unroll
      for (int kk = 0; kk < 2; ++kk) {
        short8 kf = *(const short8*)&sK[(nt * 16 + laneN) * LDQ + kk * 32 + laneQ * 8];
        s[nt] = __builtin_amdgcn_mfma_f32_16x16x32_bf16(qf[kk], kf, s[nt], 0, 0, 0);
      }
    }

    // ---- row softmax (wave-local 16-row stripe; reduce over laneN via xor-shuffles) ----
    #pragma unroll
    for (int r = 0; r < 4; ++r) {
      float mx = fmaxf(fmaxf(s[0][r], s[1][r]), fmaxf(s[2][r], s[3][r]));
      mx = fmaxf(mx, __shfl_xor(mx, 1));
      mx = fmaxf(mx, __shfl_xor(mx, 2));
      mx = fmaxf(mx, __shfl_xor(mx, 4));
      mx = fmaxf(mx, __shfl_xor(mx, 8));
      float e0 = __expf(s[0][r] - mx), e1 = __expf(s[1][r] - mx);
      float e2 = __expf(s[2][r] - mx), e3 = __expf(s[3][r] - mx);
      float sum = e0 + e1 + e2 + e3;
      sum += __shfl_xor(sum, 1);
      sum += __shfl_xor(sum, 2);
      sum += __shfl_xor(sum, 4);
      sum += __shfl_xor(sum, 8);
      float inv = __builtin_amdgcn_rcpf(sum);
      int row = m0s + laneQ * 4 + r;
      sP[row * LDP +  0 + laneN] = __float2bfloat16(e0 * inv);
      sP[row * LDP + 16 + laneN] = __float2bfloat16(e1 * inv);
      sP[row * LDP + 32 + laneN] = __float2bfloat16(e2 * inv);
      sP[row * LDP + 48 + laneN] = __float2bfloat16(e3 * inv);
    }

    // ---- O = P @ V (wave-local: A rows were written by this wave) ----
    floatx4 o0 = fzero, o1 = fzero;
    #pragma unroll
    for (int kk = 0; kk < 2; ++kk) {
      short8 pf = *(const short8*)&sP[(m0s + laneN) * LDP + kk * 32 + laneQ * 8];
      short8 v0 = *(const short8*)&sVt[(laneN) * LDV + kk * 32 + laneQ * 8];
      short8 v1 = *(const short8*)&sVt[(16 + laneN) * LDV + kk * 32 + laneQ * 8];
      o0 = __builtin_amdgcn_mfma_f32_16x16x32_bf16(pf, v0, o0, 0, 0, 0);
      o1 = __builtin_amdgcn_mfma_f32_16x16x32_bf16(pf, v1, o1, 0, 0, 0);
    }
    __hip_bfloat16* Ob = Obuf + (size_t)b * 64 * 256 + h * 32;
    #pragma unroll
    for (int r = 0; r < 4; ++r) {
      int row = m0s + laneQ * 4 + r;
      Ob[row * 256 +  0 + laneN] = __float2bfloat16(o0[r]);
      Ob[row * 256 + 16 + laneN] = __float2bfloat16(o1[r]);
    }
    __syncthreads();   // protect sQ/sK/sVt/sP for next head
  }
}

// ---------------- kernel 3: proj GEMM (65536x256)@(256x256) + bias -> FP32 out ----------------
__global__ __launch_bounds__(256, 2) void proj_kernel(
    const __hip_bfloat16* __restrict__ Ob, const __hip_bfloat16* __restrict__ pw,
    const float* __restrict__ pb, float* __restrict__ out)
{
  const int lane = threadIdx.x & 63, w = threadIdx.x >> 6;
  const int laneN = lane & 15, laneQ = lane >> 4;
  const int row0 = (blockIdx.x >> 1) * 128 + (w >> 1) * 64;
  const int col0 = (blockIdx.x & 1) * 128 + (w & 1) * 64;
  const floatx4 fzero = {0.f, 0.f, 0.f, 0.f};
  floatx4 acc[4][4];
  #pragma unroll
  for (int mt = 0; mt < 4; ++mt)
    #pragma unroll
    for (int nt = 0; nt < 4; ++nt) acc[mt][nt] = fzero;

  #pragma unroll
  for (int kk = 0; kk < 8; ++kk) {
    short8 af[4], bfr[4];
    #pragma unroll
    for (int mt = 0; mt < 4; ++mt)
      af[mt] = *(const short8*)&Ob[(size_t)(row0 + mt * 16 + laneN) * 256 + kk * 32 + laneQ * 8];
    #pragma unroll
    for (int nt = 0; nt < 4; ++nt)
      bfr[nt] = *(const short8*)&pw[(size_t)(col0 + nt * 16 + laneN) * 256 + kk * 32 + laneQ * 8];
    #pragma unroll
    for (int mt = 0; mt < 4; ++mt)
      #pragma unroll
      for (int nt = 0; nt < 4; ++nt)
        acc[mt][nt] = __builtin_amdgcn_mfma_f32_16x16x32_bf16(af[mt], bfr[nt], acc[mt][nt], 0, 0, 0);
  }

  #pragma unroll
  for (int nt = 0; nt < 4; ++nt) {
    float bias = pb[col0 + nt * 16 + laneN];
    #pragma unroll
    for (int mt = 0; mt < 4; ++mt)
      #pragma unroll
      for (int r = 0; r < 4; ++r) {
        size_t row = row0 + mt * 16 + laneQ * 4 + r;
        out[row * 256 + col0 + nt * 16 + laneN] = acc[mt][nt][r] + bias;  // fp32 store
      }
  }
}

extern "C" void kernel_launch(void* const* d_in, const int* in_sizes, int n_in,
                              void* d_out, int out_size, void* d_ws, size_t ws_size,
                              hipStream_t stream) {
  const float* x      = (const float*)d_in[0];
  const float* D      = (const float*)d_in[1];
  const float* a_p    = (const float*)d_in[2];
  const float* b_p    = (const float*)d_in[3];
  const float* a_r    = (const float*)d_in[4];
  const float* b_r    = (const float*)d_in[5];
  const float* qkv_w  = (const float*)d_in[6];
  const float* qkv_b  = (const float*)d_in[7];
  const float* proj_w = (const float*)d_in[8];
  const float* proj_b = (const float*)d_in[9];

  __hip_bfloat16* wq   = (__hip_bfloat16*)d_ws;        // 196608 bf16
  __hip_bfloat16* pw   = wq + 196608;                  // 65536 bf16
  __hip_bfloat16* Obuf = pw + 65536;                   // 16777216 bf16 (~32 MB)
  float* out = (float*)d_out;

  prep_kernel<<<256, 256, 0, stream>>>(qkv_w, proj_w, wq);
  attn_kernel<<<1024, 256, 0, stream>>>(x, D, a_p, b_p, a_r, b_r, wq, qkv_b, Obuf);
  proj_kernel<<<1024, 256, 0, stream>>>(Obuf, pw, proj_b, out);
}

// Round 4
// 210.802 us; speedup vs baseline: 1.3036x; 1.3036x over previous
//
#include <hip/hip_runtime.h>
#include <hip/hip_bf16.h>

// WindowAttention — single fused kernel per window (qkv + biased attn + proj).
// Inputs fp32, compute bf16 MFMA, output fp32.
// B=1024 windows, N=64 tokens, H=8 heads, hd=32, DIM=256, P=4.
// Fourier biases folded into QK^T as 16 extra K-dims (verified in r3):
//   Q-side k=32+idx holds raw feats [c_p|s_p|ca_p|sa_p]; K-side holds
//   per-head coefficient-mixed feats; k=48..63 zero; a_r[0],a_p[0] drop in softmax.
// Block = 512 threads (8 waves), 1 block/CU (160.8 KB LDS), 4 barriers total.

using short8  = __attribute__((ext_vector_type(8))) short;
using floatx4 = __attribute__((ext_vector_type(4))) float;

#define PI_F    3.14159265358979323846f
#define SCALE_F 0.17677669529663687f   // 32^-0.5

// ---------------- kernel 1: weights fp32 -> bf16 into ws ----------------
__global__ void prep_kernel(const float* __restrict__ qw,
                            const float* __restrict__ pw,
                            __hip_bfloat16* __restrict__ dst) {
  int g = blockIdx.x * 256 + threadIdx.x;  // 65536 threads, one float4 each
  const float4* src;
  __hip_bfloat16* d;
  if (g < 49152) { src = (const float4*)qw + g; d = dst + g * 4; }
  else { int g2 = g - 49152; src = (const float4*)pw + g2; d = dst + 196608 + g2 * 4; }
  float4 v = *src;
  d[0] = __float2bfloat16(v.x);
  d[1] = __float2bfloat16(v.y);
  d[2] = __float2bfloat16(v.z);
  d[3] = __float2bfloat16(v.w);
}

__device__ __forceinline__ void fourier_feats(float dv, int col, float* f) {
  float s1, c1; __sincosf(PI_F * dv, &s1, &c1);
  float c2 = c1*c1 - s1*s1, s2 = 2.f*s1*c1;
  float c3 = c2*c1 - s2*s1, s3 = s2*c1 + c2*s1;
  float c4 = c2*c2 - s2*s2, s4 = 2.f*s2*c2;
  float sa1, ca1; __sincosf((2.f * PI_F / 64.f) * (float)col, &sa1, &ca1);
  float ca2 = ca1*ca1 - sa1*sa1, sa2 = 2.f*sa1*ca1;
  float ca3 = ca2*ca1 - sa2*sa1, sa3 = sa2*ca1 + ca2*sa1;
  float ca4 = ca2*ca2 - sa2*sa2, sa4 = 2.f*sa2*ca2;
  f[0]=c1;  f[1]=c2;  f[2]=c3;  f[3]=c4;
  f[4]=s1;  f[5]=s2;  f[6]=s3;  f[7]=s4;
  f[8]=ca1; f[9]=ca2; f[10]=ca3; f[11]=ca4;
  f[12]=sa1; f[13]=sa2; f[14]=sa3; f[15]=sa4;
}

// ---------------- kernel 2: fully fused per-window ----------------
__global__ __launch_bounds__(512, 2) void fused_kernel(
    const float* __restrict__ x, const float* __restrict__ D,
    const float* __restrict__ a_p, const float* __restrict__ b_p,
    const float* __restrict__ a_r, const float* __restrict__ b_r,
    const __hip_bfloat16* __restrict__ wq, const float* __restrict__ qkv_b,
    const __hip_bfloat16* __restrict__ pwb, const float* __restrict__ pb,
    float* __restrict__ out)
{
  constexpr int LDX = 264, LDQ = 264, LDK = 264, LDQf = 40, LDKm = 136,
                LDVt = 72, LDP = 72, LDO = 264;
  // sScr: phase1 = x tile [64][264]; phase2 = per-wave P stripes [16][72]; phase3 = O [64][264]
  __shared__ __align__(16) __hip_bfloat16 sScr[64 * 264];   // 33792 B
  __shared__ __align__(16) __hip_bfloat16 sQ  [64 * 264];   // 33792 B (cols 0..255 = scaled q, all heads)
  __shared__ __align__(16) __hip_bfloat16 sK  [64 * 264];   // 33792 B (cols 0..255 = k, all heads)
  __shared__ __align__(16) __hip_bfloat16 sQf [64 * 40];    //  5120 B (feats 0..15, zeros 16..31)
  __shared__ __align__(16) __hip_bfloat16 sKm [64 * 136];   // 17408 B (h*16+idx, 8 heads)
  __shared__ __align__(16) __hip_bfloat16 sVt [256 * 72];   // 36864 B ([dim][token])
  // total 160768 B -> 1 block/CU

  const int tid = threadIdx.x;
  const int lane = tid & 63, w = tid >> 6;          // 8 waves
  const int laneN = lane & 15, laneQ = lane >> 4;
  const int b = blockIdx.x;
  const floatx4 fzero = {0.f, 0.f, 0.f, 0.f};
  const short8 zero8 = {0, 0, 0, 0, 0, 0, 0, 0};

  // ---- phase 0: stage x -> sScr (fp32->bf16); Q-side feats -> sQf ----
  const float4* xg = (const float4*)(x + (size_t)b * 16384);
  #pragma unroll
  for (int it = 0; it < 8; ++it) {
    int g = tid + it * 512;
    float4 v = xg[g];
    int t = g >> 6, c = (g & 63) * 4;
    __hip_bfloat16* p = &sScr[t * LDX + c];
    p[0] = __float2bfloat16(v.x); p[1] = __float2bfloat16(v.y);
    p[2] = __float2bfloat16(v.z); p[3] = __float2bfloat16(v.w);
  }
  if (tid < 64) {
    float f[16];
    fourier_feats(D[b * 64 + tid], tid & 7, f);
    #pragma unroll
    for (int i = 0; i < 16; ++i) sQf[tid * LDQf + i] = __float2bfloat16(f[i]);
    #pragma unroll
    for (int i = 16; i < 32; ++i) sQf[tid * LDQf + i] = __float2bfloat16(0.f);
  }
  __syncthreads();   // barrier A

  // ---- phase 1a: K-side mixed feats (thread -> (token, head)) ----
  {
    int t = tid >> 3, hh = tid & 7;
    float f[16];
    fourier_feats(D[b * 64 + t], t & 7, f);
    #pragma unroll
    for (int p = 0; p < 4; ++p) {
      float ar = a_r[(p + 1) * 8 + hh], br = b_r[p * 8 + hh];
      float ap = a_p[(p + 1) * 8 + hh], bp = b_p[p * 8 + hh];
      float cr = f[p], sr = f[4 + p], ca = f[8 + p], sa = f[12 + p];
      sKm[t * LDKm + hh * 16 +  0 + p] = __float2bfloat16((ar * cr + br * sr) * 0.25f);
      sKm[t * LDKm + hh * 16 +  4 + p] = __float2bfloat16((ar * sr - br * cr) * 0.25f);
      sKm[t * LDKm + hh * 16 +  8 + p] = __float2bfloat16((ap * ca - bp * sa) * 0.25f);
      sKm[t * LDKm + hh * 16 + 12 + p] = __float2bfloat16((ap * sa + bp * ca) * 0.25f);
    }
  }

  // ---- phase 1b: qkv GEMM 64x768 = sScr(64x256) @ wq^T; wave = all 4 M x 6 N-tiles ----
  short8 afq[4][8];
  #pragma unroll
  for (int mt = 0; mt < 4; ++mt)
    #pragma unroll
    for (int kk = 0; kk < 8; ++kk)
      afq[mt][kk] = *(const short8*)&sScr[(mt * 16 + laneN) * LDX + kk * 32 + laneQ * 8];

  #pragma unroll
  for (int ni = 0; ni < 6; ++ni) {
    int col0 = (w * 6 + ni) * 16;           // global qkv column [0,768)
    float bias = qkv_b[col0 + laneN];
    short8 bq[8];
    #pragma unroll
    for (int kk = 0; kk < 8; ++kk)
      bq[kk] = *(const short8*)&wq[(size_t)(col0 + laneN) * 256 + kk * 32 + laneQ * 8];
    floatx4 acc[4] = {fzero, fzero, fzero, fzero};
    #pragma unroll
    for (int kk = 0; kk < 8; ++kk)
      #pragma unroll
      for (int mt = 0; mt < 4; ++mt)
        acc[mt] = __builtin_amdgcn_mfma_f32_16x16x32_bf16(afq[mt][kk], bq[kk], acc[mt], 0, 0, 0);
    if (col0 < 256) {
      #pragma unroll
      for (int mt = 0; mt < 4; ++mt)
        #pragma unroll
        for (int r = 0; r < 4; ++r)
          sQ[(mt * 16 + laneQ * 4 + r) * LDQ + col0 + laneN] =
              __float2bfloat16((acc[mt][r] + bias) * SCALE_F);
    } else if (col0 < 512) {
      #pragma unroll
      for (int mt = 0; mt < 4; ++mt)
        #pragma unroll
        for (int r = 0; r < 4; ++r)
          sK[(mt * 16 + laneQ * 4 + r) * LDK + (col0 - 256) + laneN] =
              __float2bfloat16(acc[mt][r] + bias);
    } else {
      int vd = col0 - 512 + laneN;
      #pragma unroll
      for (int mt = 0; mt < 4; ++mt)
        #pragma unroll
        for (int r = 0; r < 4; ++r)
          sVt[vd * LDVt + (mt * 16 + laneQ * 4 + r)] = __float2bfloat16(acc[mt][r] + bias);
    }
  }
  __syncthreads();   // barrier B

  // ---- phase 2: attention, one head per wave (h = w) ----
  const int h = w;
  short8 qf0[4], qf1[4], kf0[4], kf1[4];
  #pragma unroll
  for (int mt = 0; mt < 4; ++mt) {
    qf0[mt] = *(const short8*)&sQ[(mt * 16 + laneN) * LDQ + h * 32 + laneQ * 8];
    qf1[mt] = *(const short8*)&sQf[(mt * 16 + laneN) * LDQf + laneQ * 8];  // k 32..63: feats|zeros
  }
  #pragma unroll
  for (int nt = 0; nt < 4; ++nt) {
    kf0[nt] = *(const short8*)&sK[(nt * 16 + laneN) * LDK + h * 32 + laneQ * 8];
    short8 km = *(const short8*)&sKm[(nt * 16 + laneN) * LDKm + h * 16 + (laneQ & 1) * 8];
    kf1[nt] = (laneQ < 2) ? km : zero8;     // k 32..47 mixed, 48..63 zero
  }
  floatx4 s[4][4];
  #pragma unroll
  for (int mt = 0; mt < 4; ++mt)
    #pragma unroll
    for (int nt = 0; nt < 4; ++nt) {
      s[mt][nt] = __builtin_amdgcn_mfma_f32_16x16x32_bf16(qf0[mt], kf0[nt], fzero, 0, 0, 0);
      s[mt][nt] = __builtin_amdgcn_mfma_f32_16x16x32_bf16(qf1[mt], kf1[nt], s[mt][nt], 0, 0, 0);
    }

  short8 vb[2][2];
  #pragma unroll
  for (int ont = 0; ont < 2; ++ont)
    #pragma unroll
    for (int kk = 0; kk < 2; ++kk)
      vb[ont][kk] = *(const short8*)&sVt[(h * 32 + ont * 16 + laneN) * LDVt + kk * 32 + laneQ * 8];

  floatx4 oacc[4][2];
  __hip_bfloat16* Pw = &sScr[w * 16 * LDP];   // wave-private 16x72 P stripe
  #pragma unroll
  for (int mt = 0; mt < 4; ++mt) {
    #pragma unroll
    for (int r = 0; r < 4; ++r) {
      float mx = fmaxf(fmaxf(s[mt][0][r], s[mt][1][r]), fmaxf(s[mt][2][r], s[mt][3][r]));
      mx = fmaxf(mx, __shfl_xor(mx, 1));
      mx = fmaxf(mx, __shfl_xor(mx, 2));
      mx = fmaxf(mx, __shfl_xor(mx, 4));
      mx = fmaxf(mx, __shfl_xor(mx, 8));
      float e0 = __expf(s[mt][0][r] - mx), e1 = __expf(s[mt][1][r] - mx);
      float e2 = __expf(s[mt][2][r] - mx), e3 = __expf(s[mt][3][r] - mx);
      float sum = e0 + e1 + e2 + e3;
      sum += __shfl_xor(sum, 1);
      sum += __shfl_xor(sum, 2);
      sum += __shfl_xor(sum, 4);
      sum += __shfl_xor(sum, 8);
      float inv = __builtin_amdgcn_rcpf(sum);
      int pr = laneQ * 4 + r;
      Pw[pr * LDP +  0 + laneN] = __float2bfloat16(e0 * inv);
      Pw[pr * LDP + 16 + laneN] = __float2bfloat16(e1 * inv);
      Pw[pr * LDP + 32 + laneN] = __float2bfloat16(e2 * inv);
      Pw[pr * LDP + 48 + laneN] = __float2bfloat16(e3 * inv);
    }
    // wave-internal write->read (compiler inserts lgkmcnt wait)
    short8 pf0 = *(const short8*)&Pw[laneN * LDP + laneQ * 8];
    short8 pf1 = *(const short8*)&Pw[laneN * LDP + 32 + laneQ * 8];
    #pragma unroll
    for (int ont = 0; ont < 2; ++ont) {
      oacc[mt][ont] = __builtin_amdgcn_mfma_f32_16x16x32_bf16(pf0, vb[ont][0], fzero, 0, 0, 0);
      oacc[mt][ont] = __builtin_amdgcn_mfma_f32_16x16x32_bf16(pf1, vb[ont][1], oacc[mt][ont], 0, 0, 0);
    }
  }
  __syncthreads();   // barrier C — all P scratch usage done

  // ---- phase 3: O -> sScr (as [64][264]), then proj GEMM 64x256 @ 256x256 ----
  #pragma unroll
  for (int mt = 0; mt < 4; ++mt)
    #pragma unroll
    for (int ont = 0; ont < 2; ++ont)
      #pragma unroll
      for (int r = 0; r < 4; ++r)
        sScr[(mt * 16 + laneQ * 4 + r) * LDO + h * 32 + ont * 16 + laneN] =
            __float2bfloat16(oacc[mt][ont][r]);
  __syncthreads();   // barrier D

  const int col0 = w * 32;   // wave's 32 output columns
  floatx4 pacc[4][2];
  #pragma unroll
  for (int mt = 0; mt < 4; ++mt) { pacc[mt][0] = fzero; pacc[mt][1] = fzero; }
  #pragma unroll
  for (int kk = 0; kk < 8; ++kk) {
    short8 pa[4], pbf[2];
    #pragma unroll
    for (int mt = 0; mt < 4; ++mt)
      pa[mt] = *(const short8*)&sScr[(mt * 16 + laneN) * LDO + kk * 32 + laneQ * 8];
    #pragma unroll
    for (int n2 = 0; n2 < 2; ++n2)
      pbf[n2] = *(const short8*)&pwb[(size_t)(col0 + n2 * 16 + laneN) * 256 + kk * 32 + laneQ * 8];
    #pragma unroll
    for (int mt = 0; mt < 4; ++mt)
      #pragma unroll
      for (int n2 = 0; n2 < 2; ++n2)
        pacc[mt][n2] = __builtin_amdgcn_mfma_f32_16x16x32_bf16(pa[mt], pbf[n2], pacc[mt][n2], 0, 0, 0);
  }
  float bias0 = pb[col0 + laneN], bias1 = pb[col0 + 16 + laneN];
  float* og = out + (size_t)b * 16384;
  #pragma unroll
  for (int mt = 0; mt < 4; ++mt)
    #pragma unroll
    for (int n2 = 0; n2 < 2; ++n2)
      #pragma unroll
      for (int r = 0; r < 4; ++r)
        og[(mt * 16 + laneQ * 4 + r) * 256 + col0 + n2 * 16 + laneN] =
            pacc[mt][n2][r] + (n2 ? bias1 : bias0);
}

extern "C" void kernel_launch(void* const* d_in, const int* in_sizes, int n_in,
                              void* d_out, int out_size, void* d_ws, size_t ws_size,
                              hipStream_t stream) {
  const float* x      = (const float*)d_in[0];
  const float* D      = (const float*)d_in[1];
  const float* a_p    = (const float*)d_in[2];
  const float* b_p    = (const float*)d_in[3];
  const float* a_r    = (const float*)d_in[4];
  const float* b_r    = (const float*)d_in[5];
  const float* qkv_w  = (const float*)d_in[6];
  const float* qkv_b  = (const float*)d_in[7];
  const float* proj_w = (const float*)d_in[8];
  const float* proj_b = (const float*)d_in[9];

  __hip_bfloat16* wq  = (__hip_bfloat16*)d_ws;   // 196608 bf16 (qkv_w)
  __hip_bfloat16* pwb = wq + 196608;             // 65536 bf16 (proj_w)
  float* out = (float*)d_out;

  prep_kernel<<<256, 256, 0, stream>>>(qkv_w, proj_w, wq);
  fused_kernel<<<1024, 512, 0, stream>>>(x, D, a_p, b_p, a_r, b_r, wq, qkv_b,
                                         pwb, proj_b, out);
}